// Round 2
// baseline (464.288 us; speedup 1.0000x reference)
//
#include <hip/hip_runtime.h>

// Problem constants (from reference)
#define BATCH   64
#define CH      3
#define H_OUT   608
#define W_OUT   608
#define H_IN    416
#define W_IN    416
#define ROW_OFF 85
#define COL_OFF 80

#define W4_OUT  (W_OUT / 4)          // 152 float4 per output row
#define W4_IN   (W_IN / 4)           // 104 float4 per input row
#define PLANE4  (H_OUT * W4_OUT)     // 92416 float4 per (b,c) output plane
#define IPLANE4 (H_IN * W4_IN)       // 43264 float4 per (b,c) input plane

#define BCHUNK  4                    // batches per thread

// native vector type: __builtin_nontemporal_{load,store} requires a
// scalar/vector type, not HIP's float4 struct
typedef float v4f __attribute__((ext_vector_type(4)));

#define SEL(o, m, v, r) \
    o.x = (m.x != 0.0f) ? v.x : r.x; \
    o.y = (m.y != 0.0f) ? v.y : r.y; \
    o.z = (m.z != 0.0f) ? v.z : r.z; \
    o.w = (m.w != 0.0f) ? v.w : r.w;

template<bool NT>
__device__ __forceinline__ v4f ldv(const v4f* p) {
    if constexpr (NT) return __builtin_nontemporal_load(p);
    else              return *p;
}

template<bool NT>
__device__ __forceinline__ void stv(const v4f& v, v4f* p) {
    if constexpr (NT) __builtin_nontemporal_store(v, p);
    else              *p = v;
}

// DIAGNOSTIC ROUND: kernel_launch runs this twice (NT=true then NT=false).
// The second launch rewrites bitwise-identical output; the dur_us delta vs
// round 1 (370 us) is the absolute kernel time of the plain variant, which
// rocprof's top-5 cutoff (fills at ~174 us) otherwise hides.
template<bool NT>
__global__ __launch_bounds__(256)
void composite_kernel(const v4f* __restrict__ img,
                      const v4f* __restrict__ ref,
                      v4f* __restrict__ out)
{
    const int i  = blockIdx.x * 256 + threadIdx.x;  // float4 position in plane
    const int b0 = blockIdx.y * BCHUNK;

    const int y  = i / W4_OUT;            // magic-mul division (const divisor)
    const int x4 = i - y * W4_OUT;

    // ref is reused 16x across the grid -> always cacheable (plain loads)
    const v4f r0 = ref[0 * PLANE4 + i];
    const v4f r1 = ref[1 * PLANE4 + i];
    const v4f r2 = ref[2 * PLANE4 + i];

    const int yy = y - ROW_OFF;
    const int xx = x4 * 4 - COL_OFF;      // multiple of 4 inside window
    const bool inw = (yy >= 0 && yy < H_IN && xx >= 0 && xx < W_IN);

    if (inw) {
        const int base = yy * W4_IN + (xx >> 2);

        // Phase 1: issue ALL 12 loads before any consumer (MLP).
        v4f v0[BCHUNK], v1[BCHUNK], vm[BCHUNK];
        #pragma unroll
        for (int j = 0; j < BCHUNK; ++j) {
            const int b = b0 + j;
            v0[j] = ldv<NT>(&img[(b * CH + 0) * IPLANE4 + base]);
            v1[j] = ldv<NT>(&img[(b * CH + 1) * IPLANE4 + base]);
            vm[j] = ldv<NT>(&img[(b * CH + 2) * IPLANE4 + base]);
        }

        // Phase 2: select + store.
        #pragma unroll
        for (int j = 0; j < BCHUNK; ++j) {
            const int b = b0 + j;
            v4f o0, o1, o2;
            SEL(o0, vm[j], v0[j], r0)
            SEL(o1, vm[j], v1[j], r1)
            SEL(o2, vm[j], vm[j], r2)
            stv<NT>(o0, &out[(b * CH + 0) * PLANE4 + i]);
            stv<NT>(o1, &out[(b * CH + 1) * PLANE4 + i]);
            stv<NT>(o2, &out[(b * CH + 2) * PLANE4 + i]);
        }
    } else {
        #pragma unroll
        for (int j = 0; j < BCHUNK; ++j) {
            const int b = b0 + j;
            stv<NT>(r0, &out[(b * CH + 0) * PLANE4 + i]);
            stv<NT>(r1, &out[(b * CH + 1) * PLANE4 + i]);
            stv<NT>(r2, &out[(b * CH + 2) * PLANE4 + i]);
        }
    }
}

extern "C" void kernel_launch(void* const* d_in, const int* in_sizes, int n_in,
                              void* d_out, int out_size, void* d_ws, size_t ws_size,
                              hipStream_t stream) {
    const v4f* img = (const v4f*)d_in[0];   // [64,3,416,416] f32
    const v4f* ref = (const v4f*)d_in[1];   // [1,3,608,608] f32
    v4f* out = (v4f*)d_out;                 // [64,3,608,608] f32

    dim3 grid(PLANE4 / 256, BATCH / BCHUNK);      // (361, 16)

    // Launch 1: current best (nontemporal) kernel -> graded output.
    composite_kernel<true><<<grid, 256, 0, stream>>>(img, ref, out);
    // Launch 2: plain-load/plain-store variant, rewrites identical values.
    // dur_us - 370 == absolute kernel time of this variant.
    composite_kernel<false><<<grid, 256, 0, stream>>>(img, ref, out);
}

// Round 3
// 374.360 us; speedup vs baseline: 1.2402x; 1.2402x over previous
//
#include <hip/hip_runtime.h>

// Problem constants (from reference)
#define BATCH   64
#define CH      3
#define H_OUT   608
#define W_OUT   608
#define H_IN    416
#define W_IN    416
#define ROW_OFF 85
#define COL_OFF 80

#define W4_OUT  (W_OUT / 4)          // 152 float4 per output row
#define W4_IN   (W_IN / 4)           // 104 float4 per input row
#define PLANE4  (H_OUT * W4_OUT)     // 92416 float4 per (b,c) output plane
#define IPLANE4 (H_IN * W4_IN)       // 43264 float4 per (b,c) input plane

#define BCHUNK  8                    // batches per thread (was 4)

// native vector type: __builtin_nontemporal_{load,store} requires a
// scalar/vector type, not HIP's float4 struct
typedef float v4f __attribute__((ext_vector_type(4)));

#define SEL(o, m, v, r) \
    o.x = (m.x != 0.0f) ? v.x : r.x; \
    o.y = (m.y != 0.0f) ? v.y : r.y; \
    o.z = (m.z != 0.0f) ? v.z : r.z; \
    o.w = (m.w != 0.0f) ? v.w : r.w;

// Measured (round 2 diagnostic): plain-variant kernel = 94 us absolute
// (417 MB mandatory traffic -> 4.5 TB/s; fills prove 6.33 TB/s / 66 us floor).
// Fixed harness overhead (poison fill + restores) ~= 276 us of dur_us.
__global__ __launch_bounds__(256)
void composite_kernel(const v4f* __restrict__ img,
                      const v4f* __restrict__ ref,
                      v4f* __restrict__ out)
{
    const int i  = blockIdx.x * 256 + threadIdx.x;  // float4 position in plane
    const int b0 = blockIdx.y * BCHUNK;

    const int y  = i / W4_OUT;            // magic-mul division (const divisor)
    const int x4 = i - y * W4_OUT;

    // ref is reused across 8 batches per thread -> plain (cacheable) loads
    const v4f r0 = ref[0 * PLANE4 + i];
    const v4f r1 = ref[1 * PLANE4 + i];
    const v4f r2 = ref[2 * PLANE4 + i];

    const int yy = y - ROW_OFF;
    const int xx = x4 * 4 - COL_OFF;      // multiple of 4 inside window
    const bool inw = (yy >= 0 && yy < H_IN && xx >= 0 && xx < W_IN);

    if (inw) {
        const int base = yy * W4_IN + (xx >> 2);

        // Phase 1: issue ALL 24 img loads before any consumer -> max MLP.
        // img is read exactly once -> nontemporal (don't pollute L2).
        v4f v0[BCHUNK], v1[BCHUNK], vm[BCHUNK];
        #pragma unroll
        for (int j = 0; j < BCHUNK; ++j) {
            const int b = b0 + j;
            v0[j] = __builtin_nontemporal_load(&img[(b * CH + 0) * IPLANE4 + base]);
            v1[j] = __builtin_nontemporal_load(&img[(b * CH + 1) * IPLANE4 + base]);
            vm[j] = __builtin_nontemporal_load(&img[(b * CH + 2) * IPLANE4 + base]);
        }

        // Phase 2: select + store. out is write-once, never re-read ->
        // nontemporal stores (stream past L2).
        #pragma unroll
        for (int j = 0; j < BCHUNK; ++j) {
            const int b = b0 + j;
            v4f o0, o1, o2;
            SEL(o0, vm[j], v0[j], r0)
            SEL(o1, vm[j], v1[j], r1)
            SEL(o2, vm[j], vm[j], r2)
            __builtin_nontemporal_store(o0, &out[(b * CH + 0) * PLANE4 + i]);
            __builtin_nontemporal_store(o1, &out[(b * CH + 1) * PLANE4 + i]);
            __builtin_nontemporal_store(o2, &out[(b * CH + 2) * PLANE4 + i]);
        }
    } else {
        #pragma unroll
        for (int j = 0; j < BCHUNK; ++j) {
            const int b = b0 + j;
            __builtin_nontemporal_store(r0, &out[(b * CH + 0) * PLANE4 + i]);
            __builtin_nontemporal_store(r1, &out[(b * CH + 1) * PLANE4 + i]);
            __builtin_nontemporal_store(r2, &out[(b * CH + 2) * PLANE4 + i]);
        }
    }
}

extern "C" void kernel_launch(void* const* d_in, const int* in_sizes, int n_in,
                              void* d_out, int out_size, void* d_ws, size_t ws_size,
                              hipStream_t stream) {
    const v4f* img = (const v4f*)d_in[0];   // [64,3,416,416] f32
    const v4f* ref = (const v4f*)d_in[1];   // [1,3,608,608] f32
    v4f* out = (v4f*)d_out;                 // [64,3,608,608] f32

    dim3 grid(PLANE4 / 256, BATCH / BCHUNK);      // (361, 8)
    composite_kernel<<<grid, 256, 0, stream>>>(img, ref, out);
}

// Round 4
// 370.654 us; speedup vs baseline: 1.2526x; 1.0100x over previous
//
#include <hip/hip_runtime.h>

// Problem constants (from reference)
#define BATCH   64
#define CH      3
#define H_OUT   608
#define W_OUT   608
#define H_IN    416
#define W_IN    416
#define ROW_OFF 85
#define COL_OFF 80

#define W4_OUT  (W_OUT / 4)          // 152 float4 per output row
#define W4_IN   (W_IN / 4)           // 104 float4 per input row
#define PLANE4  (H_OUT * W4_OUT)     // 92416 float4 per (b,c) output plane
#define IPLANE4 (H_IN * W4_IN)       // 43264 float4 per (b,c) input plane

#define BCHUNK  4                    // batches per thread (best measured: round 1)

// native vector type: __builtin_nontemporal_{load,store} requires a
// scalar/vector type, not HIP's float4 struct
typedef float v4f __attribute__((ext_vector_type(4)));

#define SEL(o, m, v, r) \
    o.x = (m.x != 0.0f) ? v.x : r.x; \
    o.y = (m.y != 0.0f) ? v.y : r.y; \
    o.z = (m.z != 0.0f) ? v.z : r.z; \
    o.w = (m.w != 0.0f) ? v.w : r.w;

// Session evidence (rounds 0-3):
//  - kernel absolute time = 94 us (round-2 double-launch diagnostic),
//    417 MB mandatory traffic -> 4.5 TB/s vs 6.33 TB/s pure-fill ceiling.
//  - fixed harness cost ~= 276-280 us of dur_us (poison fill 1.136 GB ~176 us
//    + input restores + launch overhead) — not addressable from the kernel.
//  - BCHUNK 4->8 (2x MLP, 2x ref reuse): null (+/- noise) -> plateau is the
//    mixed read/write stream structure, not issue/latency. Roofline reached.
__global__ __launch_bounds__(256)
void composite_kernel(const v4f* __restrict__ img,
                      const v4f* __restrict__ ref,
                      v4f* __restrict__ out)
{
    const int i  = blockIdx.x * 256 + threadIdx.x;  // float4 position in plane
    const int b0 = blockIdx.y * BCHUNK;

    const int y  = i / W4_OUT;            // magic-mul division (const divisor)
    const int x4 = i - y * W4_OUT;

    // ref is reused 16x across the grid -> keep it cacheable (plain loads)
    const v4f r0 = ref[0 * PLANE4 + i];
    const v4f r1 = ref[1 * PLANE4 + i];
    const v4f r2 = ref[2 * PLANE4 + i];

    const int yy = y - ROW_OFF;
    const int xx = x4 * 4 - COL_OFF;      // multiple of 4 inside window
    const bool inw = (yy >= 0 && yy < H_IN && xx >= 0 && xx < W_IN);

    if (inw) {
        const int base = yy * W4_IN + (xx >> 2);

        // Phase 1: issue ALL 12 loads before any consumer (MLP).
        // img is read exactly once -> nontemporal (don't pollute L2).
        v4f v0[BCHUNK], v1[BCHUNK], vm[BCHUNK];
        #pragma unroll
        for (int j = 0; j < BCHUNK; ++j) {
            const int b = b0 + j;
            v0[j] = __builtin_nontemporal_load(&img[(b * CH + 0) * IPLANE4 + base]);
            v1[j] = __builtin_nontemporal_load(&img[(b * CH + 1) * IPLANE4 + base]);
            vm[j] = __builtin_nontemporal_load(&img[(b * CH + 2) * IPLANE4 + base]);
        }

        // Phase 2: select + store. out is write-once, never re-read ->
        // nontemporal stores (stream past L2).
        #pragma unroll
        for (int j = 0; j < BCHUNK; ++j) {
            const int b = b0 + j;
            v4f o0, o1, o2;
            SEL(o0, vm[j], v0[j], r0)
            SEL(o1, vm[j], v1[j], r1)
            SEL(o2, vm[j], vm[j], r2)
            __builtin_nontemporal_store(o0, &out[(b * CH + 0) * PLANE4 + i]);
            __builtin_nontemporal_store(o1, &out[(b * CH + 1) * PLANE4 + i]);
            __builtin_nontemporal_store(o2, &out[(b * CH + 2) * PLANE4 + i]);
        }
    } else {
        #pragma unroll
        for (int j = 0; j < BCHUNK; ++j) {
            const int b = b0 + j;
            __builtin_nontemporal_store(r0, &out[(b * CH + 0) * PLANE4 + i]);
            __builtin_nontemporal_store(r1, &out[(b * CH + 1) * PLANE4 + i]);
            __builtin_nontemporal_store(r2, &out[(b * CH + 2) * PLANE4 + i]);
        }
    }
}

extern "C" void kernel_launch(void* const* d_in, const int* in_sizes, int n_in,
                              void* d_out, int out_size, void* d_ws, size_t ws_size,
                              hipStream_t stream) {
    const v4f* img = (const v4f*)d_in[0];   // [64,3,416,416] f32
    const v4f* ref = (const v4f*)d_in[1];   // [1,3,608,608] f32
    v4f* out = (v4f*)d_out;                 // [64,3,608,608] f32

    dim3 grid(PLANE4 / 256, BATCH / BCHUNK);      // (361, 16)
    composite_kernel<<<grid, 256, 0, stream>>>(img, ref, out);
}